// Round 7
// baseline (471.349 us; speedup 1.0000x reference)
//
#include <hip/hip_runtime.h>

// Cost volume: out[b, dy*9+dx, h, w] = leaky( mean_c c1[b,c,h,w] * warped[b,c,h+dy-4,w+dx-4] )
// B=8 C=192 H=128 W=160, 81 offsets, fp32, zero-padded borders.
//
// R10: MLP-batched channel loop. R4-R9 post-mortem: time pinned ~240us across
// WPT/CSPLIT/depth/FETCH variants; VALUBusy ~25%, HBM ~10%, L2 ~50% -> no
// classical wall. Per-wave duty ~10% => ~1500cy exposed stall per channel
// step: loads return at congested L3/HBM-class latency and 6-12 outstanding
// loads per wave cannot cover it. Fix: process channels in groups of GC=6 -
// issue ALL 24 loads of the group back-to-back (6 named register sets), then
// sched_barrier(0), then compute all 6 channels. MLP=24 by program order (the
// fence stops loads sinking below it); ONE latency window per 6 channels.
// launch_bounds(256,3) caps VGPR at ~170 (need ~150: 36 acc + 96 group) ->
// 3 waves/SIMD, no spill (R5's failure mode excluded by the cap arithmetic).
//
// Guards: VGPR must land 120-170 (batch materialized); WRITE_SIZE ~52 MB (no
// spill). If time stays ~240us with VGPR confirming -> latency theory wrong,
// next round = LDS h-tile kernel.
//
// Kept from R7/R8: XCD pinning (b = blockIdx&7; FETCH 579->128 MB), saddr
// 32-bit offsets computed once, mask-free inner loop with epilogue
// edge-zeroing (W: clamped o0/o2 + zero acc entries with window col outside
// image; H: clamped row + vrow-zeroed outputs, matching zero-padded ref).

namespace {
constexpr int SR  = 4;
constexpr int MO  = 9;               // 2*SR+1
constexpr int NB  = 8;
constexpr int NC  = 192;
constexpr int GC  = 6;               // channels per load-batch group
constexpr int NH  = 128;
constexpr int NW  = 160;
constexpr int HW  = NH * NW;
constexpr int WPT = 4;               // w pixels per thread
constexpr int NG  = NW / WPT;        // 40 w-groups
constexpr int UPH = MO * NG;         // 360 units per (b,h)
constexpr int NT  = 256;
constexpr int UNITS = NB * NH * UPH; // 368640
constexpr int NBLK  = UNITS / NT;    // 1440 blocks = 8 batches x 180
}

__global__ __launch_bounds__(NT, 3)
void costvol_kernel(const float* __restrict__ c1,
                    const float* __restrict__ warped,
                    const float* __restrict__ alphap,
                    float* __restrict__ out)
{
    // XCD pinning: batch = blockIdx % 8 (one batch per XCD's L2).
    const int b  = blockIdx.x & (NB - 1);
    const int u  = (blockIdx.x >> 3) * NT + threadIdx.x;   // 0 .. 46079
    const int g  = u % NG;
    const int dy = (u / NG) % MO;
    const int h  = u / UPH;

    const int w0 = g * WPT;
    const int hr = h + dy - SR;
    const bool vrow = (unsigned)hr < (unsigned)NH;
    const int hrc = vrow ? hr : (hr < 0 ? 0 : NH - 1);

    // three aligned 16B loads covering w0-4 .. w0+7; edge lanes clamp the
    // OOB load in-row (garbage confined to known acc entries).
    const int o0 = (g == 0)      ? w0 : (w0 - 4);
    const int o2 = (g == NG - 1) ? w0 : (w0 + 4);
    const bool e0 = (g == 0);
    const bool e1 = (g == NG - 1);

    // uniform bases; per-lane 32-bit offsets computed once (saddr form)
    const float* wB = warped + (size_t)b * NC * HW;
    const float* cB = c1     + (size_t)b * NC * HW;
    const int rw = hrc * NW;
    const int woff0 = rw + o0;
    const int woff1 = rw + w0;
    const int woff2 = rw + o2;
    const int coff  = h * NW + w0;

    float acc[MO][WPT];
#pragma unroll
    for (int i = 0; i < MO; ++i)
#pragma unroll
        for (int j = 0; j < WPT; ++j) acc[i][j] = 0.0f;

    // six named per-channel register sets (no runtime indexing -> no scratch)
    float4 A0, A1, A2, A3;
    float4 B0, B1, B2, B3;
    float4 C0, C1_, C2, C3;
    float4 D0, D1, D2, D3;
    float4 E0, E1, E2, E3;
    float4 F0, F1, F2, F3;

#define ISSUE(ch, X0, X1, X2, X3)                          \
    {                                                      \
        const float* wq = wB + (size_t)(ch) * HW;          \
        const float* cq = cB + (size_t)(ch) * HW;          \
        X0 = *(const float4*)(wq + woff0);                 \
        X1 = *(const float4*)(wq + woff1);                 \
        X2 = *(const float4*)(wq + woff2);                 \
        X3 = *(const float4*)(cq + coff);                  \
    }

#define COMPUTE(X0, X1, X2, X3)                            \
    {                                                      \
        const float win[12] = {                            \
            X0.x, X0.y, X0.z, X0.w,                        \
            X1.x, X1.y, X1.z, X1.w,                        \
            X2.x, X2.y, X2.z, X2.w };                      \
        const float cv[WPT] = { X3.x, X3.y, X3.z, X3.w };  \
        _Pragma("unroll")                                  \
        for (int dx = 0; dx < MO; ++dx)                    \
            _Pragma("unroll")                              \
            for (int j = 0; j < WPT; ++j)                  \
                acc[dx][j] = fmaf(cv[j], win[j + dx], acc[dx][j]); \
    }

    // 32 groups of 6 channels: 24 loads issued back-to-back, one fence,
    // then 216 FMAs. One latency window per group instead of per channel.
#pragma unroll 1
    for (int c = 0; c < NC; c += GC) {
        ISSUE(c + 0, A0, A1, A2, A3);
        ISSUE(c + 1, B0, B1, B2, B3);
        ISSUE(c + 2, C0, C1_, C2, C3);
        ISSUE(c + 3, D0, D1, D2, D3);
        ISSUE(c + 4, E0, E1, E2, E3);
        ISSUE(c + 5, F0, F1, F2, F3);
        __builtin_amdgcn_sched_barrier(0);
        COMPUTE(A0, A1, A2, A3);
        COMPUTE(B0, B1, B2, B3);
        COMPUTE(C0, C1_, C2, C3);
        COMPUTE(D0, D1, D2, D3);
        COMPUTE(E0, E1, E2, E3);
        COMPUTE(F0, F1, F2, F3);
    }
#undef ISSUE
#undef COMPUTE

    // epilogue: mean + leaky relu.
    //  - invalid warped row -> whole thread's outputs are 0
    //  - W-edge: acc[dx][j] with window col s=j+dx out of image -> exactly 0
    const float scale = 1.0f / (float)NC;
    const float al = alphap[0];
    float* op = out + ((size_t)b * (MO * MO) + (size_t)(dy * MO)) * HW
                    + (size_t)h * NW + w0;
#pragma unroll
    for (int dx = 0; dx < MO; ++dx) {
        float r[WPT];
#pragma unroll
        for (int j = 0; j < WPT; ++j) {
            const int s = j + dx;
            float vv = acc[dx][j] * scale;
            const bool bad = (!vrow) || (e0 && (s < 4)) || (e1 && (s >= 8));
            vv = bad ? 0.0f : vv;
            r[j] = (vv >= 0.0f) ? vv : al * vv;
        }
        *(float4*)(op + (size_t)dx * HW) = make_float4(r[0], r[1], r[2], r[3]);
    }
}

extern "C" void kernel_launch(void* const* d_in, const int* in_sizes, int n_in,
                              void* d_out, int out_size, void* d_ws, size_t ws_size,
                              hipStream_t stream) {
    (void)in_sizes; (void)n_in; (void)out_size; (void)d_ws; (void)ws_size;
    const float* c1     = (const float*)d_in[0];
    const float* warped = (const float*)d_in[1];
    const float* alpha  = (const float*)d_in[2];
    float* out          = (float*)d_out;
    costvol_kernel<<<dim3(NBLK), dim3(NT), 0, stream>>>(c1, warped, alpha, out);
}